// Round 11
// baseline (15664.590 us; speedup 1.0000x reference)
//
#include <hip/hip_runtime.h>
#include <stdint.h>

#define TT 256
#define BB 64
#define EE 512
#define HH 1024
#define RLX __ATOMIC_RELAXED
#define AGT __HIP_MEMORY_SCOPE_AGENT

typedef short s8v __attribute__((ext_vector_type(8)));
typedef float f4v __attribute__((ext_vector_type(4)));
typedef unsigned short u16;

static __device__ __forceinline__ u16 f2bf(float f) {
  uint32_t u = __float_as_uint(f);
  return (u16)((u + 0x7fffu + ((u >> 16) & 1u)) >> 16);  // RNE
}
static __device__ __forceinline__ float bf2f(u16 b) {
  return __uint_as_float(((uint32_t)b) << 16);
}
static __device__ __forceinline__ void split8(const float4 f0, const float4 f1,
                                              s8v& a0, s8v& a1) {
  const float tf[8] = {f0.x, f0.y, f0.z, f0.w, f1.x, f1.y, f1.z, f1.w};
#pragma unroll
  for (int e = 0; e < 8; ++e) {
    const u16 h = f2bf(tf[e]);
    a0[e] = (short)h;
    a1[e] = (short)f2bf(tf[e] - bf2f(h));
  }
}
#define MFMA __builtin_amdgcn_mfma_f32_16x16x32_bf16

struct P {
  const int* ids; const int* lens; const float* emb;
  const float* bih[2][2]; const float* bhh[2][2];  // [layer][unit]
  const u16* W[2][2][2];   // [layer][unit][plane hi/mid], frag-ready
  float* out;              // [2][T][B][2][H] f32
  u16 *h0pl, *y0pl, *h1pl; // [par][unit][plane][64][1024] bf16
  float *hF0, *hF1;        // [par][unit][64][1024] f32 carried h
  float *c0, *c1;          // [unit][64][1024] f32
  uint32_t* bar;
};

// Split f32 weights into hi/mid bf16 planes, frag-ready layout (R9-proven):
// dst[jb][kt][kg][c][e], k = kt*32+kg*8+e, gate-col n = (c>>3)*H + jb*8 + (c&7)
__global__ void prep_w(const float* Wih, const float* Whh, int KX, int K,
                       u16* dH, u16* dM) {
  const size_t total = (size_t)128 * K * 32;
  for (size_t idx = (size_t)blockIdx.x * 256 + threadIdx.x; idx < total;
       idx += (size_t)gridDim.x * 256) {
    const int c = (int)(idx & 31);
    const int k = (int)((idx >> 5) % K);
    const int jb = (int)(idx / ((size_t)K * 32));
    const int n = (c >> 3) * HH + jb * 8 + (c & 7);
    const float v = (k < KX) ? Wih[(size_t)n * KX + k] : Whh[(size_t)n * HH + (k - KX)];
    const u16 h = f2bf(v);
    const u16 m = f2bf(v - bf2f(h));
    const size_t off = ((size_t)jb * (K / 32) + (k >> 5)) * 1024 +
                       ((k >> 3) & 3) * 256 + c * 8 + (k & 7);
    dH[off] = h; dM[off] = m;
  }
}

__global__ void prep_zero_bar(uint32_t* bar) { if (threadIdx.x == 0) *bar = 0; }

__global__ __launch_bounds__(512) void elmo_persist(P p) {
  __shared__ __align__(16) u16 ldsM0[16384];       // L0 mid, kt 0..15  (32 KB)
  __shared__ __align__(16) u16 ldsM1[49152];       // L1 mid, kt 16..63 (96 KB)
  __shared__ float epi[2][4][64][8];               // 16 KB partial-sum exchange
  const int tid = threadIdx.x;
  const int wid = tid >> 6, l = tid & 63, lr = l & 15, kg = l >> 4;
  const int g = wid >> 2, kq = wid & 3;            // group (=layer), k-quarter
  const int bid = blockIdx.x;
  const int unit = bid >> 7, jb = bid & 127;
  const int dir = unit;
  const size_t PL = 65536;

  // ---- LDS weight staging (once) ----
  {
    const uint4* s0 = (const uint4*)(p.W[0][unit][1] + (size_t)jb * 48 * 1024);
    const uint4* s1 = (const uint4*)(p.W[1][unit][1] + (size_t)jb * 64 * 1024 + 16384);
    uint4* d0 = (uint4*)ldsM0; uint4* d1 = (uint4*)ldsM1;
    for (int i = tid; i < 2048; i += 512) d0[i] = s0[i];
    for (int i = tid; i < 6144; i += 512) d1[i] = s1[i];
  }
  // ---- consumer-thread constants ----
  const int tg = tid - g * 256;
  const int colp = (tg & 3) * 2;
  const int jcol = jb * 8 + colp;
  float bias2[4][2]; int len4[4];
  if (tg < 64) {
#pragma unroll
    for (int gi = 0; gi < 4; ++gi)
#pragma unroll
      for (int uu = 0; uu < 2; ++uu)
        bias2[gi][uu] = p.bih[g][unit][gi * HH + jcol + uu] +
                        p.bhh[g][unit][gi * HH + jcol + uu];
#pragma unroll
    for (int rt = 0; rt < 4; ++rt) len4[rt] = p.lens[rt * 16 + (tg >> 2)];
  }
  __syncthreads();

  if (g == 0) {  // =========== LAYER 0 group ===========
    s8v wfh[12][2], wfm[8][2];
    const u16* WH = p.W[0][unit][0] + (size_t)jb * 48 * 1024;
    const u16* WM = p.W[0][unit][1] + (size_t)jb * 48 * 1024;
#pragma unroll
    for (int i = 0; i < 12; ++i) {
      const int kt = kq + 4 * i;
#pragma unroll
      for (int ct = 0; ct < 2; ++ct)
        wfh[i][ct] = *(const s8v*)(WH + kt * 1024 + kg * 256 + (ct * 16 + lr) * 8);
    }
#pragma unroll
    for (int i = 0; i < 8; ++i) {
      const int kt = kq + 4 * (i + 4);
#pragma unroll
      for (int ct = 0; ct < 2; ++ct)
        wfm[i][ct] = *(const s8v*)(WM + kt * 1024 + kg * 256 + (ct * 16 + lr) * 8);
    }
    float* cS = p.c0 + (size_t)unit * PL;
#pragma unroll 1
    for (int it = 0; it <= TT; ++it) {
      const int s = it;
      const bool act = (s < TT);
      const int t = dir ? (TT - 1 - s) : s;
      f4v acc[4][2];
#pragma unroll
      for (int rt = 0; rt < 4; ++rt)
#pragma unroll
        for (int ct = 0; ct < 2; ++ct) { f4v z = {0.f,0.f,0.f,0.f}; acc[rt][ct] = z; }
      if (act) {
        int idr[4];
#pragma unroll
        for (int rt = 0; rt < 4; ++rt) idr[rt] = p.ids[t * BB + rt * 16 + lr];
#pragma unroll
        for (int i = 0; i < 4; ++i) {  // x part (kt 0..15)
          const int kt = kq + 4 * i;
          const int k0 = kt * 32 + kg * 8;
#pragma unroll
          for (int rt = 0; rt < 4; ++rt) {
            const float* xs = p.emb + (size_t)idr[rt] * EE + k0;
            s8v a0, a1;
            split8(*(const float4*)xs, *(const float4*)(xs + 4), a0, a1);
#pragma unroll
            for (int ct = 0; ct < 2; ++ct) {
              const s8v bm = *(const s8v*)(ldsM0 + kt * 1024 + kg * 256 + (ct * 16 + lr) * 8);
              acc[rt][ct] = MFMA(a0, wfh[i][ct], acc[rt][ct], 0, 0, 0);
              acc[rt][ct] = MFMA(a0, bm, acc[rt][ct], 0, 0, 0);
              acc[rt][ct] = MFMA(a1, wfh[i][ct], acc[rt][ct], 0, 0, 0);
            }
          }
        }
        if (s > 0) {
          const u16* hhi = p.h0pl + (((size_t)((s - 1) & 1) * 2 + unit) * 2) * PL;
          const u16* hmi = hhi + PL;
#pragma unroll
          for (int i = 0; i < 8; ++i) {  // h part (kt 16..47)
            const int kt = kq + 4 * (i + 4);
            const int kh = (kt - 16) * 32 + kg * 8;
#pragma unroll
            for (int rt = 0; rt < 4; ++rt) {
              const int row = rt * 16 + lr;
              const s8v a0 = *(const s8v*)(hhi + (size_t)row * HH + kh);
              const s8v a1 = *(const s8v*)(hmi + (size_t)row * HH + kh);
#pragma unroll
              for (int ct = 0; ct < 2; ++ct) {
                acc[rt][ct] = MFMA(a0, wfh[i + 4][ct], acc[rt][ct], 0, 0, 0);
                acc[rt][ct] = MFMA(a0, wfm[i][ct], acc[rt][ct], 0, 0, 0);
                acc[rt][ct] = MFMA(a1, wfh[i + 4][ct], acc[rt][ct], 0, 0, 0);
              }
            }
          }
        }
      }
      // ---- epilogue: 4 phases ----
      u16* h0hiC = p.h0pl + (((size_t)(s & 1) * 2 + unit) * 2) * PL;
      u16* h0miC = h0hiC + PL;
      u16* y0hiC = p.y0pl + (((size_t)(s & 1) * 2 + unit) * 2) * PL;
      u16* y0miC = y0hiC + PL;
      float* hFc = p.hF0 + ((size_t)(s & 1) * 2 + unit) * PL;
      const float* hFp = p.hF0 + ((size_t)((s - 1) & 1) * 2 + unit) * PL;
      for (int rt = 0; rt < 4; ++rt) {
        if (act) {
          *(f4v*)&epi[0][kq][l][0] = acc[rt][0];
          *(f4v*)&epi[0][kq][l][4] = acc[rt][1];
        }
        __syncthreads();
        if (act && tg < 64) {
          const int rowin = tg >> 2;
          const int row = rt * 16 + rowin;
          const int kgc = rowin >> 2, qc = rowin & 3;
          const bool m = (t < len4[rt]);
          float outv[2]; u16 hh2[2], hm2[2], yh2[2], ym2[2];
#pragma unroll
          for (int uu = 0; uu < 2; ++uu) {
            float g4[4];
#pragma unroll
            for (int gi = 0; gi < 4; ++gi) {
              const int c = gi * 8 + colp + uu;
              const int lrc = c & 15, ctc = c >> 4;
              float ssum = bias2[gi][uu];
#pragma unroll
              for (int k = 0; k < 4; ++k) ssum += epi[0][k][kgc * 16 + lrc][ctc * 4 + qc];
              g4[gi] = ssum;
            }
            const size_t hx = (size_t)row * HH + jcol + uu;
            const float c0v = (s > 0) ? cS[hx] : 0.f;
            const float iv = 1.f / (1.f + expf(-g4[0]));
            const float fv = 1.f / (1.f + expf(-g4[1]));
            const float gv = tanhf(g4[2]);
            const float ov = 1.f / (1.f + expf(-g4[3]));
            const float cn = fv * c0v + iv * gv;
            const float hn = ov * tanhf(cn);
            cS[hx] = m ? cn : c0v;
            const float hp0 = (s > 0) ? hFp[hx] : 0.f;
            const float hc = m ? hn : hp0;
            hFc[hx] = hc;
            hh2[uu] = f2bf(hc); hm2[uu] = f2bf(hc - bf2f(hh2[uu]));
            const float y = m ? hn : 0.f;
            outv[uu] = y;
            yh2[uu] = f2bf(y); ym2[uu] = f2bf(y - bf2f(yh2[uu]));
          }
          const size_t orow = ((size_t)(dir * TT + t) * BB + row) * (2 * HH);
          p.out[orow + jcol] = outv[0];
          p.out[orow + jcol + 1] = outv[1];
          const size_t px = (size_t)row * HH + jcol;
          __hip_atomic_store((uint32_t*)(h0hiC + px), (uint32_t)hh2[0] | ((uint32_t)hh2[1] << 16), RLX, AGT);
          __hip_atomic_store((uint32_t*)(h0miC + px), (uint32_t)hm2[0] | ((uint32_t)hm2[1] << 16), RLX, AGT);
          __hip_atomic_store((uint32_t*)(y0hiC + px), (uint32_t)yh2[0] | ((uint32_t)yh2[1] << 16), RLX, AGT);
          __hip_atomic_store((uint32_t*)(y0miC + px), (uint32_t)ym2[0] | ((uint32_t)ym2[1] << 16), RLX, AGT);
        }
        __syncthreads();
      }
      // ---- grid barrier ----
      __syncthreads();
      if (tid == 0) {
        __builtin_amdgcn_fence(__ATOMIC_RELEASE, "agent");
        __hip_atomic_fetch_add(p.bar, 1u, RLX, AGT);
        const uint32_t tgt = 256u * (uint32_t)(it + 1);
        int gd = 0;
        while (__hip_atomic_load(p.bar, RLX, AGT) < tgt && gd < (1 << 22)) {
          __builtin_amdgcn_s_sleep(8); ++gd;
        }
        __builtin_amdgcn_fence(__ATOMIC_ACQUIRE, "agent");
      }
      __syncthreads();
    }
  } else {  // =========== LAYER 1 group ===========
    s8v wfh[16][2], wfm[4][2];
    const u16* WH = p.W[1][unit][0] + (size_t)jb * 64 * 1024;
    const u16* WM = p.W[1][unit][1] + (size_t)jb * 64 * 1024;
#pragma unroll
    for (int i = 0; i < 16; ++i) {
      const int kt = kq + 4 * i;
#pragma unroll
      for (int ct = 0; ct < 2; ++ct)
        wfh[i][ct] = *(const s8v*)(WH + kt * 1024 + kg * 256 + (ct * 16 + lr) * 8);
    }
#pragma unroll
    for (int i = 0; i < 4; ++i) {
      const int kt = kq + 4 * i;
#pragma unroll
      for (int ct = 0; ct < 2; ++ct)
        wfm[i][ct] = *(const s8v*)(WM + kt * 1024 + kg * 256 + (ct * 16 + lr) * 8);
    }
    float* cS = p.c1 + (size_t)unit * PL;
#pragma unroll 1
    for (int it = 0; it <= TT; ++it) {
      const int u = it - 1;
      const bool act = (it >= 1);
      const int t = dir ? (TT - 1 - u) : u;
      f4v acc[4][2];
#pragma unroll
      for (int rt = 0; rt < 4; ++rt)
#pragma unroll
        for (int ct = 0; ct < 2; ++ct) { f4v z = {0.f,0.f,0.f,0.f}; acc[rt][ct] = z; }
      if (act) {
        const u16* yhi = p.y0pl + (((size_t)(u & 1) * 2 + unit) * 2) * PL;
        const u16* ymi = yhi + PL;
#pragma unroll
        for (int i = 0; i < 8; ++i) {  // y0 part (kt 0..31)
          const int kt = kq + 4 * i;
          const int k0 = kt * 32 + kg * 8;
#pragma unroll
          for (int rt = 0; rt < 4; ++rt) {
            const int row = rt * 16 + lr;
            const s8v a0 = *(const s8v*)(yhi + (size_t)row * HH + k0);
            const s8v a1 = *(const s8v*)(ymi + (size_t)row * HH + k0);
#pragma unroll
            for (int ct = 0; ct < 2; ++ct) {
              const s8v bm = (i < 4) ? wfm[i & 3][ct]
                  : *(const s8v*)(ldsM1 + (kt - 16) * 1024 + kg * 256 + (ct * 16 + lr) * 8);
              acc[rt][ct] = MFMA(a0, wfh[i][ct], acc[rt][ct], 0, 0, 0);
              acc[rt][ct] = MFMA(a0, bm, acc[rt][ct], 0, 0, 0);
              acc[rt][ct] = MFMA(a1, wfh[i][ct], acc[rt][ct], 0, 0, 0);
            }
          }
        }
        if (u > 0) {
          const u16* hhi = p.h1pl + (((size_t)((u - 1) & 1) * 2 + unit) * 2) * PL;
          const u16* hmi = hhi + PL;
#pragma unroll
          for (int i = 8; i < 16; ++i) {  // h1 part (kt 32..63)
            const int kt = kq + 4 * i;
            const int kh = (kt - 32) * 32 + kg * 8;
#pragma unroll
            for (int rt = 0; rt < 4; ++rt) {
              const int row = rt * 16 + lr;
              const s8v a0 = *(const s8v*)(hhi + (size_t)row * HH + kh);
              const s8v a1 = *(const s8v*)(hmi + (size_t)row * HH + kh);
#pragma unroll
              for (int ct = 0; ct < 2; ++ct) {
                const s8v bm = *(const s8v*)(ldsM1 + (kt - 16) * 1024 + kg * 256 + (ct * 16 + lr) * 8);
                acc[rt][ct] = MFMA(a0, wfh[i][ct], acc[rt][ct], 0, 0, 0);
                acc[rt][ct] = MFMA(a0, bm, acc[rt][ct], 0, 0, 0);
                acc[rt][ct] = MFMA(a1, wfh[i][ct], acc[rt][ct], 0, 0, 0);
              }
            }
          }
        }
      }
      u16* h1hiC = p.h1pl + (((size_t)(u & 1) * 2 + unit) * 2) * PL;
      u16* h1miC = h1hiC + PL;
      float* hFc = p.hF1 + ((size_t)(u & 1) * 2 + unit) * PL;
      const float* hFp = p.hF1 + ((size_t)((u - 1) & 1) * 2 + unit) * PL;
      for (int rt = 0; rt < 4; ++rt) {
        if (act) {
          *(f4v*)&epi[1][kq][l][0] = acc[rt][0];
          *(f4v*)&epi[1][kq][l][4] = acc[rt][1];
        }
        __syncthreads();
        if (act && tg < 64) {
          const int rowin = tg >> 2;
          const int row = rt * 16 + rowin;
          const int kgc = rowin >> 2, qc = rowin & 3;
          const bool m = (t < len4[rt]);
          const size_t orow = ((size_t)(dir * TT + t) * BB + row) * (2 * HH);
          u16 hh2[2], hm2[2];
#pragma unroll
          for (int uu = 0; uu < 2; ++uu) {
            float g4[4];
#pragma unroll
            for (int gi = 0; gi < 4; ++gi) {
              const int c = gi * 8 + colp + uu;
              const int lrc = c & 15, ctc = c >> 4;
              float ssum = bias2[gi][uu];
#pragma unroll
              for (int k = 0; k < 4; ++k) ssum += epi[1][k][kgc * 16 + lrc][ctc * 4 + qc];
              g4[gi] = ssum;
            }
            const size_t hx = (size_t)row * HH + jcol + uu;
            const float c0v = (u > 0) ? cS[hx] : 0.f;
            const float iv = 1.f / (1.f + expf(-g4[0]));
            const float fv = 1.f / (1.f + expf(-g4[1]));
            const float gv = tanhf(g4[2]);
            const float ov = 1.f / (1.f + expf(-g4[3]));
            const float cn = fv * c0v + iv * gv;
            const float hn = ov * tanhf(cn);
            cS[hx] = m ? cn : c0v;
            const float hp0 = (u > 0) ? hFp[hx] : 0.f;
            const float hc = m ? hn : hp0;
            hFc[hx] = hc;
            hh2[uu] = f2bf(hc); hm2[uu] = f2bf(hc - bf2f(hh2[uu]));
            const float y0v = p.out[orow + jcol + uu];        // own block's L0 write
            p.out[orow + HH + jcol + uu] = m ? (hn + y0v) : 0.f;
          }
          const size_t px = (size_t)row * HH + jcol;
          __hip_atomic_store((uint32_t*)(h1hiC + px), (uint32_t)hh2[0] | ((uint32_t)hh2[1] << 16), RLX, AGT);
          __hip_atomic_store((uint32_t*)(h1miC + px), (uint32_t)hm2[0] | ((uint32_t)hm2[1] << 16), RLX, AGT);
        }
        __syncthreads();
      }
      __syncthreads();
      // tid==0 is not in this branch; barrier counts still match (2 syncs)
      __syncthreads();
    }
  }
}

extern "C" void kernel_launch(void* const* d_in, const int* in_sizes, int n_in,
                              void* d_out, int out_size, void* d_ws, size_t ws_size,
                              hipStream_t stream) {
  if (n_in != 19) return;
  if (in_sizes[0] != TT * BB || in_sizes[1] != BB) return;
  if (in_sizes[2] != 32000 * EE) return;
  if (in_sizes[3] != 4 * HH * EE || in_sizes[4] != 4 * HH * HH) return;
  if (in_sizes[7] != 4 * HH * HH || in_sizes[8] != 4 * HH * HH) return;
  if (in_sizes[11] != 4 * HH * EE || in_sizes[15] != 4 * HH * HH) return;
  if (out_size != 2 * TT * BB * 2 * HH) return;
  if (ws_size < 128974976u) return;  // loud fail

  char* ws = (char*)d_ws;
  u16* WA = (u16*)ws;                        // 50,331,648 B
  u16* WB = (u16*)(ws + 50331648);           // 67,108,864 B -> 117,440,512
  u16* h0pl = (u16*)(ws + 117440512);        //  2,097,152
  u16* y0pl = (u16*)(ws + 119537664);        //  2,097,152
  u16* h1pl = (u16*)(ws + 121634816);        //  2,097,152
  float* hF0 = (float*)(ws + 123731968);     //  2,097,152
  float* hF1 = (float*)(ws + 125829120);     //  2,097,152
  float* c0  = (float*)(ws + 127926272);     //    524,288
  float* c1  = (float*)(ws + 128450560);     //    524,288 -> 128,974,848
  uint32_t* bar = (uint32_t*)(ws + 128974848);

  P p;
  p.ids = (const int*)d_in[0];
  p.lens = (const int*)d_in[1];
  p.emb = (const float*)d_in[2];
  const float* WihA[2] = {(const float*)d_in[3], (const float*)d_in[11]};
  const float* WhhA[2] = {(const float*)d_in[4], (const float*)d_in[12]};
  p.bih[0][0] = (const float*)d_in[5];  p.bhh[0][0] = (const float*)d_in[6];
  p.bih[0][1] = (const float*)d_in[13]; p.bhh[0][1] = (const float*)d_in[14];
  const float* WihB[2] = {(const float*)d_in[7], (const float*)d_in[15]};
  const float* WhhB[2] = {(const float*)d_in[8], (const float*)d_in[16]};
  p.bih[1][0] = (const float*)d_in[9];  p.bhh[1][0] = (const float*)d_in[10];
  p.bih[1][1] = (const float*)d_in[17]; p.bhh[1][1] = (const float*)d_in[18];
  for (int u = 0; u < 2; ++u) {
    p.W[0][u][0] = WA + (size_t)(u * 2 + 0) * 6291456;
    p.W[0][u][1] = WA + (size_t)(u * 2 + 1) * 6291456;
    p.W[1][u][0] = WB + (size_t)(u * 2 + 0) * 8388608;
    p.W[1][u][1] = WB + (size_t)(u * 2 + 1) * 8388608;
  }
  p.out = (float*)d_out;
  p.h0pl = h0pl; p.y0pl = y0pl; p.h1pl = h1pl;
  p.hF0 = hF0; p.hF1 = hF1; p.c0 = c0; p.c1 = c1;
  p.bar = bar;

  for (int u = 0; u < 2; ++u) {
    prep_w<<<4096, 256, 0, stream>>>(WihA[u], WhhA[u], EE, 1536,
                                     (u16*)p.W[0][u][0], (u16*)p.W[0][u][1]);
    prep_w<<<4096, 256, 0, stream>>>(WihB[u], WhhB[u], HH, 2048,
                                     (u16*)p.W[1][u][0], (u16*)p.W[1][u][1]);
  }
  prep_zero_bar<<<1, 64, 0, stream>>>(bar);
  void* kargs[] = {&p};
  hipLaunchCooperativeKernel(reinterpret_cast<void*>(&elmo_persist),
                             dim3(256), dim3(512), kargs, 0, stream);
}

// Round 12
// 15518.867 us; speedup vs baseline: 1.0094x; 1.0094x over previous
//
#include <hip/hip_runtime.h>
#include <stdint.h>

#define TT 256
#define BB 64
#define EE 512
#define HH 1024
#define RLX __ATOMIC_RELAXED
#define AGT __HIP_MEMORY_SCOPE_AGENT

typedef short s8v __attribute__((ext_vector_type(8)));
typedef float f4v __attribute__((ext_vector_type(4)));
typedef unsigned short u16;

static __device__ __forceinline__ u16 f2bf(float f) {
  uint32_t u = __float_as_uint(f);
  return (u16)((u + 0x7fffu + ((u >> 16) & 1u)) >> 16);  // RNE
}
static __device__ __forceinline__ float bf2f(u16 b) {
  return __uint_as_float(((uint32_t)b) << 16);
}
static __device__ __forceinline__ void split8(const float4 f0, const float4 f1,
                                              s8v& a0, s8v& a1) {
  const float tf[8] = {f0.x, f0.y, f0.z, f0.w, f1.x, f1.y, f1.z, f1.w};
#pragma unroll
  for (int e = 0; e < 8; ++e) {
    const u16 h = f2bf(tf[e]);
    a0[e] = (short)h;
    a1[e] = (short)f2bf(tf[e] - bf2f(h));
  }
}
#define MFMA __builtin_amdgcn_mfma_f32_16x16x32_bf16

struct P {
  const int* ids; const int* lens; const float* emb;
  const float* bih[2][2]; const float* bhh[2][2];  // [layer][unit]
  const u16* W[2][2][2];   // [layer][unit][plane hi/mid], frag-ready
  float* out;              // [2][T][B][2][H] f32
  u16 *h0pl, *y0pl, *h1pl; // [par][unit][plane][64][1024] bf16
  float *hF0, *hF1;        // [par][unit][64][1024] f32 carried h
  float *c0, *c1;          // [unit][64][1024] f32
  uint32_t* bar;
};

// Split f32 weights into hi/mid bf16 planes, frag-ready layout (R9-proven):
// dst[jb][kt][kg][c][e], k = kt*32+kg*8+e, gate-col n = (c>>3)*H + jb*8 + (c&7)
__global__ void prep_w(const float* Wih, const float* Whh, int KX, int K,
                       u16* dH, u16* dM) {
  const size_t total = (size_t)128 * K * 32;
  for (size_t idx = (size_t)blockIdx.x * 256 + threadIdx.x; idx < total;
       idx += (size_t)gridDim.x * 256) {
    const int c = (int)(idx & 31);
    const int k = (int)((idx >> 5) % K);
    const int jb = (int)(idx / ((size_t)K * 32));
    const int n = (c >> 3) * HH + jb * 8 + (c & 7);
    const float v = (k < KX) ? Wih[(size_t)n * KX + k] : Whh[(size_t)n * HH + (k - KX)];
    const u16 h = f2bf(v);
    const u16 m = f2bf(v - bf2f(h));
    const size_t off = ((size_t)jb * (K / 32) + (k >> 5)) * 1024 +
                       ((k >> 3) & 3) * 256 + c * 8 + (k & 7);
    dH[off] = h; dM[off] = m;
  }
}

__global__ void prep_zero_bar(uint32_t* bar) { if (threadIdx.x == 0) *bar = 0; }

__global__ __launch_bounds__(512)
__attribute__((amdgpu_waves_per_eu(2, 2)))  // cap occupancy target -> 256-VGPR budget
void elmo_persist(P p) {
  __shared__ __align__(16) u16 ldsM0[16384];       // L0 mid, kt 0..15  (32 KB)
  __shared__ __align__(16) u16 ldsM1[49152];       // L1 mid, kt 16..63 (96 KB)
  __shared__ float epi[2][4][64][8];               // 16 KB partial-sum exchange
  const int tid = threadIdx.x;
  const int wid = tid >> 6, l = tid & 63, lr = l & 15, kg = l >> 4;
  const int g = wid >> 2, kq = wid & 3;            // group (=layer), k-quarter
  const int bid = blockIdx.x;
  const int unit = bid >> 7, jb = bid & 127;
  const int dir = unit;
  const size_t PL = 65536;

  // ---- LDS weight staging (once) ----
  {
    const uint4* s0 = (const uint4*)(p.W[0][unit][1] + (size_t)jb * 48 * 1024);
    const uint4* s1 = (const uint4*)(p.W[1][unit][1] + (size_t)jb * 64 * 1024 + 16384);
    uint4* d0 = (uint4*)ldsM0; uint4* d1 = (uint4*)ldsM1;
    for (int i = tid; i < 2048; i += 512) d0[i] = s0[i];
    for (int i = tid; i < 6144; i += 512) d1[i] = s1[i];
  }
  // ---- consumer-thread constants ----
  const int tg = tid - g * 256;
  const int colp = (tg & 3) * 2;
  const int jcol = jb * 8 + colp;
  float bias2[4][2]; int len4[4];
  if (tg < 64) {
#pragma unroll
    for (int gi = 0; gi < 4; ++gi)
#pragma unroll
      for (int uu = 0; uu < 2; ++uu)
        bias2[gi][uu] = p.bih[g][unit][gi * HH + jcol + uu] +
                        p.bhh[g][unit][gi * HH + jcol + uu];
#pragma unroll
    for (int rt = 0; rt < 4; ++rt) len4[rt] = p.lens[rt * 16 + (tg >> 2)];
  }
  __syncthreads();

  if (g == 0) {  // =========== LAYER 0 group ===========
    s8v wfh[12][2], wfm[8][2];
    const u16* WH = p.W[0][unit][0] + (size_t)jb * 48 * 1024;
    const u16* WM = p.W[0][unit][1] + (size_t)jb * 48 * 1024;
#pragma unroll
    for (int i = 0; i < 12; ++i) {
      const int kt = kq + 4 * i;
#pragma unroll
      for (int ct = 0; ct < 2; ++ct)
        wfh[i][ct] = *(const s8v*)(WH + kt * 1024 + kg * 256 + (ct * 16 + lr) * 8);
    }
#pragma unroll
    for (int i = 0; i < 8; ++i) {
      const int kt = kq + 4 * (i + 4);
#pragma unroll
      for (int ct = 0; ct < 2; ++ct)
        wfm[i][ct] = *(const s8v*)(WM + kt * 1024 + kg * 256 + (ct * 16 + lr) * 8);
    }
    float* cS = p.c0 + (size_t)unit * PL;
#pragma unroll 1
    for (int it = 0; it <= TT; ++it) {
      const int s = it;
      const bool act = (s < TT);
      const int t = dir ? (TT - 1 - s) : s;
      f4v acc[4][2];
#pragma unroll
      for (int rt = 0; rt < 4; ++rt)
#pragma unroll
        for (int ct = 0; ct < 2; ++ct) { f4v z = {0.f,0.f,0.f,0.f}; acc[rt][ct] = z; }
      if (act) {
        int idr[4];
#pragma unroll
        for (int rt = 0; rt < 4; ++rt) idr[rt] = p.ids[t * BB + rt * 16 + lr];
#pragma unroll
        for (int i = 0; i < 4; ++i) {  // x part (kt 0..15)
          const int kt = kq + 4 * i;
          const int k0 = kt * 32 + kg * 8;
#pragma unroll
          for (int rt = 0; rt < 4; ++rt) {
            const float* xs = p.emb + (size_t)idr[rt] * EE + k0;
            s8v a0, a1;
            split8(*(const float4*)xs, *(const float4*)(xs + 4), a0, a1);
#pragma unroll
            for (int ct = 0; ct < 2; ++ct) {
              const s8v bm = *(const s8v*)(ldsM0 + kt * 1024 + kg * 256 + (ct * 16 + lr) * 8);
              acc[rt][ct] = MFMA(a0, wfh[i][ct], acc[rt][ct], 0, 0, 0);
              acc[rt][ct] = MFMA(a0, bm, acc[rt][ct], 0, 0, 0);
              acc[rt][ct] = MFMA(a1, wfh[i][ct], acc[rt][ct], 0, 0, 0);
            }
          }
        }
        if (s > 0) {
          const u16* hhi = p.h0pl + (((size_t)((s - 1) & 1) * 2 + unit) * 2) * PL;
          const u16* hmi = hhi + PL;
#pragma unroll
          for (int i = 0; i < 8; ++i) {  // h part (kt 16..47)
            const int kt = kq + 4 * (i + 4);
            const int kh = (kt - 16) * 32 + kg * 8;
#pragma unroll
            for (int rt = 0; rt < 4; ++rt) {
              const int row = rt * 16 + lr;
              const s8v a0 = *(const s8v*)(hhi + (size_t)row * HH + kh);
              const s8v a1 = *(const s8v*)(hmi + (size_t)row * HH + kh);
#pragma unroll
              for (int ct = 0; ct < 2; ++ct) {
                acc[rt][ct] = MFMA(a0, wfh[i + 4][ct], acc[rt][ct], 0, 0, 0);
                acc[rt][ct] = MFMA(a0, wfm[i][ct], acc[rt][ct], 0, 0, 0);
                acc[rt][ct] = MFMA(a1, wfh[i + 4][ct], acc[rt][ct], 0, 0, 0);
              }
            }
          }
        }
      }
      // ---- epilogue: 4 phases ----
      u16* h0hiC = p.h0pl + (((size_t)(s & 1) * 2 + unit) * 2) * PL;
      u16* h0miC = h0hiC + PL;
      u16* y0hiC = p.y0pl + (((size_t)(s & 1) * 2 + unit) * 2) * PL;
      u16* y0miC = y0hiC + PL;
      float* hFc = p.hF0 + ((size_t)(s & 1) * 2 + unit) * PL;
      const float* hFp = p.hF0 + ((size_t)((s - 1) & 1) * 2 + unit) * PL;
      for (int rt = 0; rt < 4; ++rt) {
        if (act) {
          *(f4v*)&epi[0][kq][l][0] = acc[rt][0];
          *(f4v*)&epi[0][kq][l][4] = acc[rt][1];
        }
        __syncthreads();
        if (act && tg < 64) {
          const int rowin = tg >> 2;
          const int row = rt * 16 + rowin;
          const int kgc = rowin >> 2, qc = rowin & 3;
          const bool m = (t < len4[rt]);
          float outv[2]; u16 hh2[2], hm2[2], yh2[2], ym2[2];
#pragma unroll
          for (int uu = 0; uu < 2; ++uu) {
            float g4[4];
#pragma unroll
            for (int gi = 0; gi < 4; ++gi) {
              const int c = gi * 8 + colp + uu;
              const int lrc = c & 15, ctc = c >> 4;
              float ssum = bias2[gi][uu];
#pragma unroll
              for (int k = 0; k < 4; ++k) ssum += epi[0][k][kgc * 16 + lrc][ctc * 4 + qc];
              g4[gi] = ssum;
            }
            const size_t hx = (size_t)row * HH + jcol + uu;
            const float c0v = (s > 0) ? cS[hx] : 0.f;
            const float iv = 1.f / (1.f + expf(-g4[0]));
            const float fv = 1.f / (1.f + expf(-g4[1]));
            const float gv = tanhf(g4[2]);
            const float ov = 1.f / (1.f + expf(-g4[3]));
            const float cn = fv * c0v + iv * gv;
            const float hn = ov * tanhf(cn);
            cS[hx] = m ? cn : c0v;
            const float hp0 = (s > 0) ? hFp[hx] : 0.f;
            const float hc = m ? hn : hp0;
            hFc[hx] = hc;
            hh2[uu] = f2bf(hc); hm2[uu] = f2bf(hc - bf2f(hh2[uu]));
            const float y = m ? hn : 0.f;
            outv[uu] = y;
            yh2[uu] = f2bf(y); ym2[uu] = f2bf(y - bf2f(yh2[uu]));
          }
          const size_t orow = ((size_t)(dir * TT + t) * BB + row) * (2 * HH);
          p.out[orow + jcol] = outv[0];
          p.out[orow + jcol + 1] = outv[1];
          const size_t px = (size_t)row * HH + jcol;
          __hip_atomic_store((uint32_t*)(h0hiC + px), (uint32_t)hh2[0] | ((uint32_t)hh2[1] << 16), RLX, AGT);
          __hip_atomic_store((uint32_t*)(h0miC + px), (uint32_t)hm2[0] | ((uint32_t)hm2[1] << 16), RLX, AGT);
          __hip_atomic_store((uint32_t*)(y0hiC + px), (uint32_t)yh2[0] | ((uint32_t)yh2[1] << 16), RLX, AGT);
          __hip_atomic_store((uint32_t*)(y0miC + px), (uint32_t)ym2[0] | ((uint32_t)ym2[1] << 16), RLX, AGT);
        }
        __syncthreads();
      }
      // ---- grid barrier ----
      __syncthreads();
      if (tid == 0) {
        __builtin_amdgcn_fence(__ATOMIC_RELEASE, "agent");
        __hip_atomic_fetch_add(p.bar, 1u, RLX, AGT);
        const uint32_t tgt = 256u * (uint32_t)(it + 1);
        int gd = 0;
        while (__hip_atomic_load(p.bar, RLX, AGT) < tgt && gd < (1 << 22)) {
          __builtin_amdgcn_s_sleep(8); ++gd;
        }
        __builtin_amdgcn_fence(__ATOMIC_ACQUIRE, "agent");
      }
      __syncthreads();
    }
  } else {  // =========== LAYER 1 group ===========
    s8v wfh[16][2], wfm[4][2];
    const u16* WH = p.W[1][unit][0] + (size_t)jb * 64 * 1024;
    const u16* WM = p.W[1][unit][1] + (size_t)jb * 64 * 1024;
#pragma unroll
    for (int i = 0; i < 16; ++i) {
      const int kt = kq + 4 * i;
#pragma unroll
      for (int ct = 0; ct < 2; ++ct)
        wfh[i][ct] = *(const s8v*)(WH + kt * 1024 + kg * 256 + (ct * 16 + lr) * 8);
    }
#pragma unroll
    for (int i = 0; i < 4; ++i) {
      const int kt = kq + 4 * i;
#pragma unroll
      for (int ct = 0; ct < 2; ++ct)
        wfm[i][ct] = *(const s8v*)(WM + kt * 1024 + kg * 256 + (ct * 16 + lr) * 8);
    }
    float* cS = p.c1 + (size_t)unit * PL;
#pragma unroll 1
    for (int it = 0; it <= TT; ++it) {
      const int u = it - 1;
      const bool act = (it >= 1);
      const int t = dir ? (TT - 1 - u) : u;
      f4v acc[4][2];
#pragma unroll
      for (int rt = 0; rt < 4; ++rt)
#pragma unroll
        for (int ct = 0; ct < 2; ++ct) { f4v z = {0.f,0.f,0.f,0.f}; acc[rt][ct] = z; }
      if (act) {
        const u16* yhi = p.y0pl + (((size_t)(u & 1) * 2 + unit) * 2) * PL;
        const u16* ymi = yhi + PL;
#pragma unroll
        for (int i = 0; i < 8; ++i) {  // y0 part (kt 0..31)
          const int kt = kq + 4 * i;
          const int k0 = kt * 32 + kg * 8;
#pragma unroll
          for (int rt = 0; rt < 4; ++rt) {
            const int row = rt * 16 + lr;
            const s8v a0 = *(const s8v*)(yhi + (size_t)row * HH + k0);
            const s8v a1 = *(const s8v*)(ymi + (size_t)row * HH + k0);
#pragma unroll
            for (int ct = 0; ct < 2; ++ct) {
              const s8v bm = (i < 4) ? wfm[i & 3][ct]
                  : *(const s8v*)(ldsM1 + (kt - 16) * 1024 + kg * 256 + (ct * 16 + lr) * 8);
              acc[rt][ct] = MFMA(a0, wfh[i][ct], acc[rt][ct], 0, 0, 0);
              acc[rt][ct] = MFMA(a0, bm, acc[rt][ct], 0, 0, 0);
              acc[rt][ct] = MFMA(a1, wfh[i][ct], acc[rt][ct], 0, 0, 0);
            }
          }
        }
        if (u > 0) {
          const u16* hhi = p.h1pl + (((size_t)((u - 1) & 1) * 2 + unit) * 2) * PL;
          const u16* hmi = hhi + PL;
#pragma unroll
          for (int i = 8; i < 16; ++i) {  // h1 part (kt 32..63)
            const int kt = kq + 4 * i;
            const int kh = (kt - 32) * 32 + kg * 8;
#pragma unroll
            for (int rt = 0; rt < 4; ++rt) {
              const int row = rt * 16 + lr;
              const s8v a0 = *(const s8v*)(hhi + (size_t)row * HH + kh);
              const s8v a1 = *(const s8v*)(hmi + (size_t)row * HH + kh);
#pragma unroll
              for (int ct = 0; ct < 2; ++ct) {
                const s8v bm = *(const s8v*)(ldsM1 + (kt - 16) * 1024 + kg * 256 + (ct * 16 + lr) * 8);
                acc[rt][ct] = MFMA(a0, wfh[i][ct], acc[rt][ct], 0, 0, 0);
                acc[rt][ct] = MFMA(a0, bm, acc[rt][ct], 0, 0, 0);
                acc[rt][ct] = MFMA(a1, wfh[i][ct], acc[rt][ct], 0, 0, 0);
              }
            }
          }
        }
      }
      u16* h1hiC = p.h1pl + (((size_t)(u & 1) * 2 + unit) * 2) * PL;
      u16* h1miC = h1hiC + PL;
      float* hFc = p.hF1 + ((size_t)(u & 1) * 2 + unit) * PL;
      const float* hFp = p.hF1 + ((size_t)((u - 1) & 1) * 2 + unit) * PL;
      for (int rt = 0; rt < 4; ++rt) {
        if (act) {
          *(f4v*)&epi[1][kq][l][0] = acc[rt][0];
          *(f4v*)&epi[1][kq][l][4] = acc[rt][1];
        }
        __syncthreads();
        if (act && tg < 64) {
          const int rowin = tg >> 2;
          const int row = rt * 16 + rowin;
          const int kgc = rowin >> 2, qc = rowin & 3;
          const bool m = (t < len4[rt]);
          const size_t orow = ((size_t)(dir * TT + t) * BB + row) * (2 * HH);
          u16 hh2[2], hm2[2];
#pragma unroll
          for (int uu = 0; uu < 2; ++uu) {
            float g4[4];
#pragma unroll
            for (int gi = 0; gi < 4; ++gi) {
              const int c = gi * 8 + colp + uu;
              const int lrc = c & 15, ctc = c >> 4;
              float ssum = bias2[gi][uu];
#pragma unroll
              for (int k = 0; k < 4; ++k) ssum += epi[1][k][kgc * 16 + lrc][ctc * 4 + qc];
              g4[gi] = ssum;
            }
            const size_t hx = (size_t)row * HH + jcol + uu;
            const float c0v = (u > 0) ? cS[hx] : 0.f;
            const float iv = 1.f / (1.f + expf(-g4[0]));
            const float fv = 1.f / (1.f + expf(-g4[1]));
            const float gv = tanhf(g4[2]);
            const float ov = 1.f / (1.f + expf(-g4[3]));
            const float cn = fv * c0v + iv * gv;
            const float hn = ov * tanhf(cn);
            cS[hx] = m ? cn : c0v;
            const float hp0 = (u > 0) ? hFp[hx] : 0.f;
            const float hc = m ? hn : hp0;
            hFc[hx] = hc;
            hh2[uu] = f2bf(hc); hm2[uu] = f2bf(hc - bf2f(hh2[uu]));
            const float y0v = p.out[orow + jcol + uu];        // own block's L0 write
            p.out[orow + HH + jcol + uu] = m ? (hn + y0v) : 0.f;
          }
          const size_t px = (size_t)row * HH + jcol;
          __hip_atomic_store((uint32_t*)(h1hiC + px), (uint32_t)hh2[0] | ((uint32_t)hh2[1] << 16), RLX, AGT);
          __hip_atomic_store((uint32_t*)(h1miC + px), (uint32_t)hm2[0] | ((uint32_t)hm2[1] << 16), RLX, AGT);
        }
        __syncthreads();
      }
      __syncthreads();
      // tid==0 is not in this branch; barrier counts still match (2 syncs)
      __syncthreads();
    }
  }
}

extern "C" void kernel_launch(void* const* d_in, const int* in_sizes, int n_in,
                              void* d_out, int out_size, void* d_ws, size_t ws_size,
                              hipStream_t stream) {
  if (n_in != 19) return;
  if (in_sizes[0] != TT * BB || in_sizes[1] != BB) return;
  if (in_sizes[2] != 32000 * EE) return;
  if (in_sizes[3] != 4 * HH * EE || in_sizes[4] != 4 * HH * HH) return;
  if (in_sizes[7] != 4 * HH * HH || in_sizes[8] != 4 * HH * HH) return;
  if (in_sizes[11] != 4 * HH * EE || in_sizes[15] != 4 * HH * HH) return;
  if (out_size != 2 * TT * BB * 2 * HH) return;
  if (ws_size < 128974976u) return;  // loud fail

  char* ws = (char*)d_ws;
  u16* WA = (u16*)ws;                        // 50,331,648 B
  u16* WB = (u16*)(ws + 50331648);           // 67,108,864 B -> 117,440,512
  u16* h0pl = (u16*)(ws + 117440512);        //  2,097,152
  u16* y0pl = (u16*)(ws + 119537664);        //  2,097,152
  u16* h1pl = (u16*)(ws + 121634816);        //  2,097,152
  float* hF0 = (float*)(ws + 123731968);     //  2,097,152
  float* hF1 = (float*)(ws + 125829120);     //  2,097,152
  float* c0  = (float*)(ws + 127926272);     //    524,288
  float* c1  = (float*)(ws + 128450560);     //    524,288 -> 128,974,848
  uint32_t* bar = (uint32_t*)(ws + 128974848);

  P p;
  p.ids = (const int*)d_in[0];
  p.lens = (const int*)d_in[1];
  p.emb = (const float*)d_in[2];
  const float* WihA[2] = {(const float*)d_in[3], (const float*)d_in[11]};
  const float* WhhA[2] = {(const float*)d_in[4], (const float*)d_in[12]};
  p.bih[0][0] = (const float*)d_in[5];  p.bhh[0][0] = (const float*)d_in[6];
  p.bih[0][1] = (const float*)d_in[13]; p.bhh[0][1] = (const float*)d_in[14];
  const float* WihB[2] = {(const float*)d_in[7], (const float*)d_in[15]};
  const float* WhhB[2] = {(const float*)d_in[8], (const float*)d_in[16]};
  p.bih[1][0] = (const float*)d_in[9];  p.bhh[1][0] = (const float*)d_in[10];
  p.bih[1][1] = (const float*)d_in[17]; p.bhh[1][1] = (const float*)d_in[18];
  for (int u = 0; u < 2; ++u) {
    p.W[0][u][0] = WA + (size_t)(u * 2 + 0) * 6291456;
    p.W[0][u][1] = WA + (size_t)(u * 2 + 1) * 6291456;
    p.W[1][u][0] = WB + (size_t)(u * 2 + 0) * 8388608;
    p.W[1][u][1] = WB + (size_t)(u * 2 + 1) * 8388608;
  }
  p.out = (float*)d_out;
  p.h0pl = h0pl; p.y0pl = y0pl; p.h1pl = h1pl;
  p.hF0 = hF0; p.hF1 = hF1; p.c0 = c0; p.c1 = c1;
  p.bar = bar;

  for (int u = 0; u < 2; ++u) {
    prep_w<<<4096, 256, 0, stream>>>(WihA[u], WhhA[u], EE, 1536,
                                     (u16*)p.W[0][u][0], (u16*)p.W[0][u][1]);
    prep_w<<<4096, 256, 0, stream>>>(WihB[u], WhhB[u], HH, 2048,
                                     (u16*)p.W[1][u][0], (u16*)p.W[1][u][1]);
  }
  prep_zero_bar<<<1, 64, 0, stream>>>(bar);
  void* kargs[] = {&p};
  hipLaunchCooperativeKernel(reinterpret_cast<void*>(&elmo_persist),
                             dim3(256), dim3(512), kargs, 0, stream);
}